// Round 9
// baseline (220.046 us; speedup 1.0000x reference)
//
#include <hip/hip_runtime.h>
#include <stdint.h>

// Problem constants
#define BB   2048
#define DIN  2048
#define UU   1024
#define KF   49
#define GM   2048         // GEMM M = batch
#define GK   3072         // GEMM K = UU + DIN
#define GN   5120         // GEMM N = 5*UU

// GEMM block geometry
#define BM   128          // batch rows per block
#define UC   32           // unit-cols per block (x5 gates = 160 GEMM cols)
#define BKS  32           // K per step (96 steps)
#define SZB  18432        // bytes per LDS buffer: A 8KB + B 10KB; 3 buffers
#define LVOFF (3 * SZB)   // v-sum exchange area: 128 x 36 floats

typedef __bf16  bf16x8 __attribute__((ext_vector_type(8)));
typedef float   f32x4  __attribute__((ext_vector_type(4)));

#define VL(dst, ptr) asm volatile("global_load_dwordx4 %0, %1, off" \
                                  : "=v"(dst) : "v"(ptr) : "memory")
#define WAITVM(n) asm volatile("s_waitcnt vmcnt(" #n ")" ::: "memory")

static __device__ __forceinline__ unsigned short f2bf(float f) {
    union { float f; unsigned u; } x; x.f = f;
    unsigned u = x.u;
    unsigned r = (u + 0x7fffu + ((u >> 16) & 1u)) >> 16;   // RNE
    return (unsigned short)r;
}

// ---------------------------------------------------------------------------
// Kernel 1: prep = buildA (blocks [0,6144)) + buildW transpose (rest)
//   A[b][k]       = bf16([h_tm | inputs])                        [GM][GK]
//   Wt2[u*5+g][k] = bf16(k<UU ? W_gates[k][g*UU+u] : U_gates[k-UU][g*UU+u])
// ---------------------------------------------------------------------------
__global__ void prep(const float* __restrict__ h, const float* __restrict__ x,
                     const float* __restrict__ Wg, const float* __restrict__ Ug,
                     unsigned short* __restrict__ A, unsigned short* __restrict__ Wt) {
    __shared__ float t[32][36];
    if (blockIdx.x < 6144) {
        int idx = blockIdx.x * 256 + threadIdx.x;    // one thread = 4 elems
        int b = idx / (GK / 4);
        int k = (idx % (GK / 4)) * 4;
        float4 v;
        if (k < UU) v = *(const float4*)(h + (size_t)b * UU + k);
        else        v = *(const float4*)(x + (size_t)b * DIN + (k - UU));
        ushort4 o;
        o.x = f2bf(v.x); o.y = f2bf(v.y); o.z = f2bf(v.z); o.w = f2bf(v.w);
        *(ushort4*)(A + (size_t)idx * 4) = o;
    } else {
        int bid2 = blockIdx.x - 6144;                // 32x32 transpose tiles
        int k0 = (bid2 % (GK / 32)) * 32;
        int n0 = (bid2 / (GK / 32)) * 32;
        int r  = threadIdx.x >> 3;                   // 0..31
        int cq = threadIdx.x & 7;                    // 0..7  (x4 floats)
        int k = k0 + r;
        const float* src = (k < UU) ? (Wg + (size_t)k * GN) : (Ug + (size_t)(k - UU) * GN);
        *(float4*)&t[r][cq * 4] = *(const float4*)(src + n0 + cq * 4);
        __syncthreads();
        int n = n0 + r;                              // original col = g*UU + u
        int u = n & (UU - 1);
        int g = n >> 10;
        ushort4 o;
        o.x = f2bf(t[cq * 4 + 0][r]);
        o.y = f2bf(t[cq * 4 + 1][r]);
        o.z = f2bf(t[cq * 4 + 2][r]);
        o.w = f2bf(t[cq * 4 + 3][r]);
        *(ushort4*)(Wt + (size_t)(u * 5 + g) * GK + k0 + cq * 4) = o;
    }
}

// ---------------------------------------------------------------------------
// Kernel 2: WAVE-SPECIALIZED fused 5-gate GEMM + v_seq stream + LSTM tail.
// Waves 0-3 (tid 0..255): GEMM, tile 128 rows x 32 ucols x 5 gates, 3-buffer
//   counted-vmcnt staging (5 global_load_lds/thread/step, vmcnt(5)).
// Waves 4-7 (tid 256..511): stream v_seq slice (128 x 49 x 32 f32) with a
//   depth-2 quad ring (4 loads/quad, vmcnt(4) + sched_barrier before consume).
// Both classes share per-step s_barrier placed in SHARED code (97 barriers,
// structurally deadlock-free). Streamers deposit sums in LDS; GEMM waves do
// gates + epilogue. grid = (32,16) = 512 blocks, 1 block/CU.
// ---------------------------------------------------------------------------
__global__ __launch_bounds__(512, 2) void gemm_fused(
        const unsigned short* __restrict__ A, const unsigned short* __restrict__ Wt,
        const float* __restrict__ m_tm, const float* __restrict__ bg,
        const float* __restrict__ v_seq, float* __restrict__ out) {
    __shared__ __align__(16) char lds[3 * SZB + 18432];   // 73,728 B

    const int tid  = threadIdx.x;
    const int lane = tid & 63;
    const int wave = tid >> 6;
    const bool isg = (wave < 4);
    const int brow  = blockIdx.y * BM;
    const int ucol0 = blockIdx.x * UC;

    // ---- GEMM state (meaningful for waves 0-3) ----
    const int wr = (wave >> 1) & 1;
    const int wc = wave & 1;
    f32x4 acc[4][5];
#pragma unroll
    for (int m = 0; m < 4; m++)
#pragma unroll
        for (int g = 0; g < 5; g++) acc[m][g] = (f32x4){0.f, 0.f, 0.f, 0.f};

    // staging map: A 512 chunks (rounds 0-1), B 640 chunks (rounds 2-4;
    // round 4 duplicated across thread halves -> uniform 5 instr/thread)
    const unsigned short* src[5];
    int ldsoff[5];
    {
        const int gt = tid & 255;
#pragma unroll
        for (int r = 0; r < 5; ++r) {
            if (r < 2) {
                int j = r * 256 + gt;
                src[r] = A + (size_t)(brow + (j >> 2)) * GK + (j & 3) * 8;
                ldsoff[r] = j * 16;
            } else {
                int j2 = (r < 4) ? (r - 2) * 256 + gt : 512 + (gt & 127);
                src[r] = Wt + (size_t)((size_t)ucol0 * 5 + (j2 >> 2)) * GK + (j2 & 3) * 8;
                ldsoff[r] = 8192 + j2 * 16;
            }
        }
    }
    const int aoff = (wr * 64 + (lane & 15)) * 64 + (lane >> 4) * 16;          // + m*1024
    const int boff = 8192 + ((wc * 16 + (lane & 15)) * 5) * 64 + (lane >> 4) * 16; // + g*64

    auto STAGE5 = [&](int ko, int bufb) {
#pragma unroll
        for (int r = 0; r < 5; ++r)
            __builtin_amdgcn_global_load_lds(
                (const __attribute__((address_space(1))) void*)(src[r] + ko),
                (__attribute__((address_space(3))) void*)(lds + bufb + ldsoff[r]), 16, 0, 0);
    };
    auto COMPUTE = [&](int bufb) {
        bf16x8 af[4], bfr[5];
#pragma unroll
        for (int m = 0; m < 4; m++) af[m]  = *(const bf16x8*)(lds + bufb + aoff + m * 1024);
#pragma unroll
        for (int g = 0; g < 5; g++) bfr[g] = *(const bf16x8*)(lds + bufb + boff + g * 64);
#pragma unroll
        for (int m = 0; m < 4; m++)
#pragma unroll
            for (int g = 0; g < 5; g++)
                acc[m][g] = __builtin_amdgcn_mfma_f32_16x16x32_bf16(af[m], bfr[g], acc[m][g], 0, 0, 0);
    };

    // ---- streamer state (meaningful for waves 4-7) ----
    const int stid = tid & 255;
    const float* vp = v_seq + (size_t)(brow + (stid >> 1)) * (KF * UU)
                    + ucol0 + (stid & 1) * 16;
    f32x4 qa0, qa1, qa2, qa3, qb0, qb1, qb2, qb3;
    f32x4 s0 = {0,0,0,0}, s1 = {0,0,0,0}, s2 = {0,0,0,0}, s3 = {0,0,0,0};

#define VQUAD(q0_,q1_,q2_,q3_, kk) do { const float* p_ = vp + (size_t)(kk) * UU; \
    VL(q0_, p_); VL(q1_, p_ + 4); VL(q2_, p_ + 8); VL(q3_, p_ + 12); } while (0)
#define SCONS(q0_,q1_,q2_,q3_) do { s0 += q0_; s1 += q1_; s2 += q2_; s3 += q3_; } while (0)
#define BAR() do { __builtin_amdgcn_s_barrier(); __builtin_amdgcn_sched_barrier(0); } while (0)

    // prologue: GEMM stages k-steps 0,1; streamers issue quad k=0
    if (isg) { STAGE5(0, 0); STAGE5(BKS, SZB); WAITVM(5); }
    else     { VQUAD(qa0, qa1, qa2, qa3, 0); }
    BAR();

    int cb = 0, sb = 2 * SZB, ko = 2 * BKS;
#define ADV() do { cb += SZB; if (cb == 3 * SZB) cb = 0; \
                   sb += SZB; if (sb == 3 * SZB) sb = 0; ko += BKS; } while (0)

    for (int grp = 0; grp < 23; ++grp) {
        // step 4g+0: streamers issue k=2g+1, consume k=2g
        if (isg) { STAGE5(ko, sb); COMPUTE(cb); WAITVM(5); }
        else { VQUAD(qb0, qb1, qb2, qb3, 2 * grp + 1); WAITVM(4);
               __builtin_amdgcn_sched_barrier(0); SCONS(qa0, qa1, qa2, qa3); }
        BAR(); ADV();
        // step 4g+1
        if (isg) { STAGE5(ko, sb); COMPUTE(cb); WAITVM(5); }
        BAR(); ADV();
        // step 4g+2: streamers issue k=2g+2, consume k=2g+1
        if (isg) { STAGE5(ko, sb); COMPUTE(cb); WAITVM(5); }
        else { VQUAD(qa0, qa1, qa2, qa3, 2 * grp + 2); WAITVM(4);
               __builtin_amdgcn_sched_barrier(0); SCONS(qb0, qb1, qb2, qb3); }
        BAR(); ADV();
        // step 4g+3
        if (isg) { STAGE5(ko, sb); COMPUTE(cb); WAITVM(5); }
        BAR(); ADV();
    }
    // t=92: stage 94, compute 92; streamers issue k=47, consume k=46
    if (isg) { STAGE5(ko, sb); COMPUTE(cb); WAITVM(5); }
    else { VQUAD(qb0, qb1, qb2, qb3, 47); WAITVM(4);
           __builtin_amdgcn_sched_barrier(0); SCONS(qa0, qa1, qa2, qa3); }
    BAR(); ADV();
    // t=93: stage 95, compute 93
    if (isg) { STAGE5(ko, sb); COMPUTE(cb); WAITVM(5); }
    BAR(); ADV();
    // t=94: compute 94, drain stage FIFO; streamers issue k=48, consume k=47
    if (isg) { COMPUTE(cb); WAITVM(0); }
    else { VQUAD(qa0, qa1, qa2, qa3, 48); WAITVM(4);
           __builtin_amdgcn_sched_barrier(0); SCONS(qb0, qb1, qb2, qb3); }
    BAR(); ADV();
    // t=95: compute 95; streamers consume k=48 and deposit sums in LDS
    if (isg) { COMPUTE(cb); }
    else {
        WAITVM(0);
        __builtin_amdgcn_sched_barrier(0);
        SCONS(qa0, qa1, qa2, qa3);
        float* lvp = (float*)(lds + LVOFF);
        const int row = stid >> 1, cbase = (stid & 1) * 16;
        *(f32x4*)&lvp[row * 36 + cbase +  0] = s0;
        *(f32x4*)&lvp[row * 36 + cbase +  4] = s1;
        *(f32x4*)&lvp[row * 36 + cbase +  8] = s2;
        *(f32x4*)&lvp[row * 36 + cbase + 12] = s3;
        asm volatile("s_waitcnt lgkmcnt(0)" ::: "memory");
    }
    __builtin_amdgcn_s_barrier();   // final: lv visible to GEMM waves
    if (!isg) return;

    // Epilogue (GEMM waves): gates + cell + sentinel + ct, write 3 outputs.
    const float* lvp = (const float*)(lds + LVOFF);
    const int ucol = ucol0 + wc * 16 + (lane & 15);
    const int lcol = wc * 16 + (lane & 15);
    const float c0 = bg[0 * UU + ucol];
    const float c1 = bg[1 * UU + ucol];
    const float c2 = bg[2 * UU + ucol];
    const float c3 = bg[3 * UU + ucol];
    const float c4 = bg[4 * UU + ucol];
    const int lr0 = wr * 64 + ((lane >> 4) << 2);
    float* out0 = out;
    float* out1 = out + (size_t)GM * UU;
    float* out2 = out + 2 * (size_t)GM * UU;
#pragma unroll
    for (int m = 0; m < 4; m++) {
#pragma unroll
        for (int j = 0; j < 4; j++) {
            const int lrow = lr0 + m * 16 + j;
            const int row  = brow + lrow;
            const size_t idx = (size_t)row * UU + ucol;
            const float vs  = lvp[lrow * 36 + lcol];
            const float mtm = m_tm[idx];
            const float f = acc[m][0][j] + c0;
            const float i = acc[m][1][j] + c1;
            const float o = acc[m][2][j] + c2;
            const float g = acc[m][3][j] + c3;
            const float a = acc[m][4][j] + c4;
            const float ft = 1.f / (1.f + __expf(-f));
            const float it = 1.f / (1.f + __expf(-i));
            const float ot = 1.f / (1.f + __expf(-o));
            const float gt = 1.f / (1.f + __expf(-g));
            const float at = tanhf(a);
            const float mtv = mtm * ft + it * at;
            const float tm  = tanhf(mtv);
            const float ht  = ot * tm;
            const float st  = gt * tm;
            out0[idx] = ht + vs + st;
            out1[idx] = ht;
            out2[idx] = mtv;
        }
    }
}

// ---------------------------------------------------------------------------
extern "C" void kernel_launch(void* const* d_in, const int* in_sizes, int n_in,
                              void* d_out, int out_size, void* d_ws, size_t ws_size,
                              hipStream_t stream) {
    (void)in_sizes; (void)n_in; (void)out_size; (void)ws_size;
    const float* inputs  = (const float*)d_in[0];
    const float* h_tm    = (const float*)d_in[1];
    const float* m_tm    = (const float*)d_in[2];
    const float* v_seq   = (const float*)d_in[3];
    const float* W_gates = (const float*)d_in[4];
    const float* U_gates = (const float*)d_in[5];
    const float* b_gates = (const float*)d_in[6];
    // d_in[7..9] (W_z, U_z, W_h) are dead: softmax over a size-1 axis == 1.

    char* ws = (char*)d_ws;
    unsigned short* Abf = (unsigned short*)ws;                  // 2048*3072*2 = 12,582,912 B
    unsigned short* Wt  = (unsigned short*)(ws + 12582912);     // 5120*3072*2 = 31,457,280 B
    float* out = (float*)d_out;

    hipLaunchKernelGGL(prep, dim3(6144 + (GK / 32) * (GN / 32)), dim3(256), 0, stream,
                       h_tm, inputs, W_gates, U_gates, Abf, Wt);
    hipLaunchKernelGGL(gemm_fused, dim3(UU / UC, GM / BM), dim3(512), 0, stream,
                       Abf, Wt, m_tm, b_gates, v_seq, out);
}